// Round 11
// baseline (4664.233 us; speedup 1.0000x reference)
//
#include <hip/hip_runtime.h>

// 3-layer LSTM (H=64, B=512, T=2048) + linear head (OUT=11), all fp32.
// One block (4 waves) per batch element; thread k owns gate row k.
// Weights pinned in VGPRs via IN-LOOP empty-asm; h/x broadcast via per-wave
// LDS; one barrier per step.
//
// History: r1 VGPR=84 (weights remat'd from L2 every step, 1950us/layer);
// r4 no-__restrict__ -> no change (88); r7 prologue-only asm pins -> NO
// change (88/1950us) -- loop-invariant values can still have their loads
// sunk into the loop. r8-r10 fix (resubmitted, broker timeouts): pin INSIDE
// the loop ("+v" redefines each weight every iteration -> loop-carried,
// opaque def -> remat from memory is illegal). Bottleneck arithmetic:
// per-step weight re-reads = 160KB/CU ~= 43 TB/s aggregate > L2 ~34.5 TB/s
// ceiling -> that IS the 2285 cyc/step. Register residency is the only fix;
// LDS staging has zero reuse (275 GB/s/CU ~= LDS ceiling, no win).
// Fallback ladder if pin fails: (1) lane-split rows (4 thr/row, ~32-float
// live set fits default allocation), (2) inline-asm FMA core.
//
// In-place safety (layers 1,2: x_in aliases hs_out):
//   - each wave's load of x[t+1] is consumed (vmcnt forced by the xbuf
//     ds_write publish) BEFORE that wave reaches barrier #(t+1);
//   - wave 0 stores h[t+1] only AFTER passing barrier #(t+1).
// Layer 2 stores only h[T-1], parked in its row's t=0 slot (verified r4/r7).

namespace {
constexpr int kH   = 64;
constexpr int kT   = 2048;
constexpr int kB   = 512;
constexpr int kOut = 11;
}

__device__ __forceinline__ float fast_rcp(float x) { return __builtin_amdgcn_rcpf(x); }

__device__ __forceinline__ float sigmoid_f(float x) {
    return fast_rcp(1.0f + __expf(-x));
}

__device__ __forceinline__ float tanh_f(float x) {
    // Valid for any |x| (c can drift over 2048 steps): e in (0,1].
    const float ax = fabsf(x);
    const float e  = __expf(-2.0f * ax);
    const float t  = (1.0f - e) * fast_rcp(1.0f + e);
    return copysignf(t, x);
}

// Re-define a float4's components as opaque VGPR values (no code emitted).
// Used INSIDE the loop: makes weights loop-carried -> remat impossible.
__device__ __forceinline__ void pin4(float4& v) {
    asm volatile("" : "+v"(v.x), "+v"(v.y), "+v"(v.z), "+v"(v.w));
}

template <int D_IN, bool STORE_ALL>
__global__
__attribute__((amdgpu_flat_work_group_size(256, 256), amdgpu_waves_per_eu(2, 2)))
void lstm_layer_kernel(const float* x_in,   // may alias hs_out (layers 1,2)
                       const float* __restrict__ Wih,
                       const float* __restrict__ Whh,
                       const float* __restrict__ bih,
                       const float* __restrict__ bhh,
                       float* hs_out)
{
    const int b    = blockIdx.x;
    const int k    = threadIdx.x;   // gate row 0..255 (i,f,g,o blocks of 64)
    const int wave = k >> 6;        // == gate type (wave-uniform activation)
    const int lane = k & 63;        // == hidden unit for the update phase

    __shared__ float hbuf[4][kH];      // per-wave h broadcast buffer
    __shared__ float xbuf[4][D_IN];    // per-wave x broadcast buffer
    __shared__ float gates[2][4 * kH]; // t-parity double-buffered activations

    // ---- weight rows -> VGPRs ----
    float4 wh4[16];
#pragma unroll
    for (int j = 0; j < 16; ++j)
        wh4[j] = *reinterpret_cast<const float4*>(&Whh[k * kH + j * 4]);

    float4 wx4[D_IN / 4 > 0 ? D_IN / 4 : 1];
    float2 wx2;
    if constexpr (D_IN == 2) {
        wx2 = *reinterpret_cast<const float2*>(&Wih[k * 2]);
    } else {
#pragma unroll
        for (int j = 0; j < D_IN / 4; ++j)
            wx4[j] = *reinterpret_cast<const float4*>(&Wih[k * D_IN + j * 4]);
    }
    float bias = bih[k] + bhh[k];

    hbuf[wave][lane] = 0.0f;   // h0 = 0 (own-wave buffer: no barrier needed)
    float c = 0.0f;            // lane's unit-c, replicated per wave

    const float* xb = x_in   + (size_t)b * kT * D_IN;
    float*       hb = hs_out + (size_t)b * kT * kH;

    float xreg = 0.0f;
    if (lane < D_IN) xreg = xb[lane];   // prefetch x_0

    for (int t = 0; t < kT; ++t) {
        // ---- IN-LOOP PINS: redefine all weights as opaque VGPR values.
        // "+v" is read-modify-write: each iteration's input must be the
        // previous iteration's asm output -> loop-carried -> the compiler
        // cannot substitute a reload of the original memory value.
#pragma unroll
        for (int j = 0; j < 16; ++j) pin4(wh4[j]);
        if constexpr (D_IN == 2) {
            asm volatile("" : "+v"(wx2.x), "+v"(wx2.y));
        } else {
#pragma unroll
            for (int j = 0; j < D_IN / 4; ++j) pin4(wx4[j]);
        }
        asm volatile("" : "+v"(bias));

        // publish x_t (ds_write consumes prefetch -> vmcnt wait before barrier)
        if (lane < D_IN) xbuf[wave][lane] = xreg;
        // prefetch x_{t+1} (clamped; last iteration re-reads x_{T-1}, unused)
        const int tn = (t + 1 < kT) ? (t + 1) : t;
        if (lane < D_IN) xreg = xb[(size_t)tn * D_IN + lane];

        // ---- gate preactivation: bias + Wih x_t + Whh h_{t-1} ----
        // 4 independent accumulator chains: dependent-issue spacing ~8 cyc
        // (wave64, SIMD-32) > ~4-cyc FMA latency.
        float a0 = bias, a1 = 0.0f, a2 = 0.0f, a3 = 0.0f;
        if constexpr (D_IN == 2) {
            a0 = fmaf(xbuf[wave][0], wx2.x, a0);
            a1 = fmaf(xbuf[wave][1], wx2.y, a1);
        } else {
#pragma unroll
            for (int j = 0; j < D_IN / 4; ++j) {
                const float4 v = *reinterpret_cast<const float4*>(&xbuf[wave][j * 4]);
                a0 = fmaf(v.x, wx4[j].x, a0);
                a1 = fmaf(v.y, wx4[j].y, a1);
                a2 = fmaf(v.z, wx4[j].z, a2);
                a3 = fmaf(v.w, wx4[j].w, a3);
            }
        }
#pragma unroll
        for (int j = 0; j < 16; ++j) {
            const float4 v = *reinterpret_cast<const float4*>(&hbuf[wave][j * 4]);
            a0 = fmaf(v.x, wh4[j].x, a0);
            a1 = fmaf(v.y, wh4[j].y, a1);
            a2 = fmaf(v.z, wh4[j].z, a2);
            a3 = fmaf(v.w, wh4[j].w, a3);
        }
        const float pre = (a0 + a1) + (a2 + a3);
        const float act = (wave == 2) ? tanh_f(pre) : sigmoid_f(pre);
        gates[t & 1][k] = act;
        __syncthreads();

        // ---- c/h update, redundant per wave (lane n owns unit n) ----
        const float gi = gates[t & 1][lane];
        const float gf = gates[t & 1][lane + 64];
        const float gg = gates[t & 1][lane + 128];
        const float go = gates[t & 1][lane + 192];
        c = fmaf(gf, c, gi * gg);
        const float h = go * tanh_f(c);
        hbuf[wave][lane] = h;                    // own-wave buffer: no barrier
        if constexpr (STORE_ALL) {
            if (wave == 0) hb[(size_t)t * kH + lane] = h;
        } else {
            // only h[T-1] is consumed downstream; park it in the t=0 slot
            // (that address was read at step 0 by this same block only).
            if (wave == 0 && t == kT - 1) hb[lane] = h;
        }
    }
}

__global__ void out_proj_kernel(const float* __restrict__ hlast, // [B][kH] rows at stride kT*kH
                                const float* __restrict__ Wout,
                                const float* __restrict__ bout,
                                float* __restrict__ out)
{
    const int b    = blockIdx.x;
    const int lane = threadIdx.x;  // 64
    const float h = hlast[(size_t)b * kT * kH + lane];
#pragma unroll
    for (int o = 0; o < kOut; ++o) {
        float p = h * Wout[o * kH + lane];
#pragma unroll
        for (int s = 32; s > 0; s >>= 1) p += __shfl_xor(p, s, 64);
        if (lane == 0) out[b * kOut + o] = p + bout[o];
    }
}

extern "C" void kernel_launch(void* const* d_in, const int* in_sizes, int n_in,
                              void* d_out, int out_size, void* d_ws, size_t ws_size,
                              hipStream_t stream)
{
    const float* x    = (const float*)d_in[0];
    const float* Wih0 = (const float*)d_in[1];
    const float* Whh0 = (const float*)d_in[2];
    const float* bih0 = (const float*)d_in[3];
    const float* bhh0 = (const float*)d_in[4];
    const float* Wih1 = (const float*)d_in[5];
    const float* Whh1 = (const float*)d_in[6];
    const float* bih1 = (const float*)d_in[7];
    const float* bhh1 = (const float*)d_in[8];
    const float* Wih2 = (const float*)d_in[9];
    const float* Whh2 = (const float*)d_in[10];
    const float* bih2 = (const float*)d_in[11];
    const float* bhh2 = (const float*)d_in[12];
    const float* Wout = (const float*)d_in[13];
    const float* bout = (const float*)d_in[14];
    (void)in_sizes; (void)n_in; (void)out_size; (void)ws_size;

    // hs buffer: B*T*H fp32 = 256 MiB in workspace; layers 1,2 run in-place.
    float* hs = (float*)d_ws;

    lstm_layer_kernel<2,  true ><<<kB, 256, 0, stream>>>(x,  Wih0, Whh0, bih0, bhh0, hs);
    lstm_layer_kernel<64, true ><<<kB, 256, 0, stream>>>(hs, Wih1, Whh1, bih1, bhh1, hs);
    lstm_layer_kernel<64, false><<<kB, 256, 0, stream>>>(hs, Wih2, Whh2, bih2, bhh2, hs);
    out_proj_kernel<<<kB, 64, 0, stream>>>(hs, Wout, bout, (float*)d_out);
}

// Round 14
// 4481.906 us; speedup vs baseline: 1.0407x; 1.0407x over previous
//
#include <hip/hip_runtime.h>

// 3-layer LSTM (H=64, B=512, T=2048) + linear head (OUT=11), all fp32.
// r13: 2-WAY LANE-SPLIT. 512 threads/block, 2 threads per gate row, each
// owning a 32-column slice (32 Whh + 32 Wih floats ~= 85-reg live set --
// under the ~88 cap the allocator enforced in r1/r4/r7/r11 regardless of
// attributes/pins, so weights stay register-resident WITHOUT fighting it).
// 64 FMA/thread/step keeps density high (4-way split would halve it).
// Cross-step x prefetch: xreg holds x[t+1], published to xsh at step t top,
// then xreg <- x[t+2] (load-to-use = one full step ~= covers HBM latency).
//
// Evidence trail: r1 84 VGPR / layers-1,2 1950us (128-float live set won't
// fit -> in-loop reloads, ~43TB/s aggregate L2 demand > 34.5 ceiling);
// r4 (-__restrict__), r7 (prologue pins), r11 (in-loop pins): allocation
// byte-identical (88/1950-1990us) -> source-level anti-remat is defeated on
// this toolchain; layer 0 (needs ~75 regs, fits) ran 715us -> residency is
// the lever. This design fits the live set under the cap structurally.
//
// Sync: ONE barrier per step. xsh/gates parity-double-buffered; hbuf is
// per-wave (own-wave write->read, DS in-order per wave). Race audit:
// write xsh[p^1]@t is post-barrier(t-1); readers of xsh[p^1] are step t-1
// (reads complete pre-barrier(t-1)) and step t+1 (post-barrier(t)). OK.
// In-place safety (layers 1,2 alias): x[t+2] load completes at its ds_write
// consumption (pre-barrier(t+1)); the only write to that address is wave 0's
// h[t+2] store, post-barrier(t+2). Layer 2 stores only h[T-1] -> t=0 slot.

namespace {
constexpr int kH   = 64;
constexpr int kT   = 2048;
constexpr int kB   = 512;
constexpr int kOut = 11;
}

__device__ __forceinline__ float fast_rcp(float x) { return __builtin_amdgcn_rcpf(x); }

__device__ __forceinline__ float sigmoid_f(float x) {
    return fast_rcp(1.0f + __expf(-x));
}

__device__ __forceinline__ float tanh_f(float x) {
    // Valid for any |x| (c can drift over 2048 steps): e in (0,1].
    const float ax = fabsf(x);
    const float e  = __expf(-2.0f * ax);
    const float t  = (1.0f - e) * fast_rcp(1.0f + e);
    return copysignf(t, x);
}

template <int D_IN, bool STORE_ALL>
__global__ __launch_bounds__(512)
void lstm_layer_kernel(const float* x_in,   // may alias hs_out (layers 1,2)
                       const float* __restrict__ Wih,
                       const float* __restrict__ Whh,
                       const float* __restrict__ bih,
                       const float* __restrict__ bhh,
                       float* hs_out)
{
    const int b    = blockIdx.x;
    const int tid  = threadIdx.x;   // 0..511
    const int row  = tid >> 1;      // gate row 0..255 (i,f,g,o blocks of 64)
    const int sub  = tid & 1;       // which 32-column half of the row
    const int wv   = tid >> 6;      // wave 0..7
    const int lane = tid & 63;      // unit for the update phase

    __shared__ float hbuf[8][kH];     // per-wave h copy (2 KB)
    __shared__ float gates[2][256];   // parity-buffered activations (2 KB)
    __shared__ float xsh[2][D_IN];    // parity-buffered x

    // ---- weight slice -> VGPRs (~64 floats + temps ~= 85 live) ----
    float4 wh[8];
#pragma unroll
    for (int j = 0; j < 8; ++j)
        wh[j] = *reinterpret_cast<const float4*>(&Whh[row * kH + sub * 32 + j * 4]);

    float4 wx[D_IN == 64 ? 8 : 1];
    float2 wx2 = {0.0f, 0.0f};
    if constexpr (D_IN == 64) {
#pragma unroll
        for (int j = 0; j < 8; ++j)
            wx[j] = *reinterpret_cast<const float4*>(&Wih[row * 64 + sub * 32 + j * 4]);
    } else {
        if (sub == 0) wx2 = *reinterpret_cast<const float2*>(&Wih[row * 2]);
    }
    const float bias = bih[row] + bhh[row];

    hbuf[wv][lane] = 0.0f;          // h0 = 0 (own-wave slice)
    float c = 0.0f;                 // unit-c, replicated per wave (lane=unit)

    const float* xb = x_in   + (size_t)b * kT * D_IN;
    float*       hb = hs_out + (size_t)b * kT * kH;

    if (tid < D_IN) xsh[0][tid] = xb[tid];          // x_0 -> LDS
    float xreg = 0.0f;
    if (tid < D_IN) xreg = xb[(size_t)D_IN + tid];  // prefetch x_1
    __syncthreads();

    for (int t = 0; t < kT; ++t) {
        const int p = t & 1;

        // ---- publish x[t+1] (consumes prefetch: vmcnt forced by ds_write),
        //      then prefetch x[t+2] (load-to-use = one full step) ----
        if (tid < D_IN) {
            xsh[p ^ 1][tid] = xreg;
            const int tn = (t + 2 < kT) ? (t + 2) : (kT - 1);
            xreg = xb[(size_t)tn * D_IN + tid];
        }

        // ---- FMA phase: partial dot over own 32-col slice ----
        float a0 = 0.0f, a1 = 0.0f, a2 = 0.0f, a3 = 0.0f;
        if constexpr (D_IN == 64) {
#pragma unroll
            for (int j = 0; j < 8; ++j) {
                const float4 xv = *reinterpret_cast<const float4*>(&xsh[p][sub * 32 + j * 4]);
                a0 = fmaf(xv.x, wx[j].x, a0);
                a1 = fmaf(xv.y, wx[j].y, a1);
                a2 = fmaf(xv.z, wx[j].z, a2);
                a3 = fmaf(xv.w, wx[j].w, a3);
            }
        } else {
            if (sub == 0) {
                a0 = fmaf(xsh[p][0], wx2.x, a0);
                a1 = fmaf(xsh[p][1], wx2.y, a1);
            }
        }
#pragma unroll
        for (int j = 0; j < 8; ++j) {
            const float4 hv = *reinterpret_cast<const float4*>(&hbuf[wv][sub * 32 + j * 4]);
            a0 = fmaf(hv.x, wh[j].x, a0);
            a1 = fmaf(hv.y, wh[j].y, a1);
            a2 = fmaf(hv.z, wh[j].z, a2);
            a3 = fmaf(hv.w, wh[j].w, a3);
        }
        float pre = (a0 + a1) + (a2 + a3);
        pre += __shfl_xor(pre, 1);      // pair reduce: both lanes get the sum
        pre += bias;                    // added once, post-reduce

        // rows 128..191 = gate g (tanh); row>>6 == tid>>7 -> wave-uniform
        const float act = ((row >> 6) == 2) ? tanh_f(pre) : sigmoid_f(pre);
        if (sub == 0) gates[p][row] = act;

        __syncthreads();   // gates[p] + xsh[p^1] published

        // ---- c/h update, redundant per wave (lane n owns unit n) ----
        const float gi = gates[p][lane];
        const float gf = gates[p][lane + 64];
        const float gg = gates[p][lane + 128];
        const float go = gates[p][lane + 192];
        c = fmaf(gf, c, gi * gg);
        const float h = go * tanh_f(c);
        hbuf[wv][lane] = h;            // own-wave slice: DS in-order per wave
        if constexpr (STORE_ALL) {
            if (wv == 0) hb[(size_t)t * kH + lane] = h;
        } else {
            // only h[T-1] is consumed downstream; park it in the t=0 slot
            // (read-complete since step 0, same block).
            if (wv == 0 && t == kT - 1) hb[lane] = h;
        }
    }
}

__global__ void out_proj_kernel(const float* __restrict__ hlast, // [B][kH] rows at stride kT*kH
                                const float* __restrict__ Wout,
                                const float* __restrict__ bout,
                                float* __restrict__ out)
{
    const int b    = blockIdx.x;
    const int lane = threadIdx.x;  // 64
    const float h = hlast[(size_t)b * kT * kH + lane];
#pragma unroll
    for (int o = 0; o < kOut; ++o) {
        float p = h * Wout[o * kH + lane];
#pragma unroll
        for (int s = 32; s > 0; s >>= 1) p += __shfl_xor(p, s, 64);
        if (lane == 0) out[b * kOut + o] = p + bout[o];
    }
}

extern "C" void kernel_launch(void* const* d_in, const int* in_sizes, int n_in,
                              void* d_out, int out_size, void* d_ws, size_t ws_size,
                              hipStream_t stream)
{
    const float* x    = (const float*)d_in[0];
    const float* Wih0 = (const float*)d_in[1];
    const float* Whh0 = (const float*)d_in[2];
    const float* bih0 = (const float*)d_in[3];
    const float* bhh0 = (const float*)d_in[4];
    const float* Wih1 = (const float*)d_in[5];
    const float* Whh1 = (const float*)d_in[6];
    const float* bih1 = (const float*)d_in[7];
    const float* bhh1 = (const float*)d_in[8];
    const float* Wih2 = (const float*)d_in[9];
    const float* Whh2 = (const float*)d_in[10];
    const float* bih2 = (const float*)d_in[11];
    const float* bhh2 = (const float*)d_in[12];
    const float* Wout = (const float*)d_in[13];
    const float* bout = (const float*)d_in[14];
    (void)in_sizes; (void)n_in; (void)out_size; (void)ws_size;

    // hs buffer: B*T*H fp32 = 256 MiB in workspace; layers 1,2 run in-place.
    float* hs = (float*)d_ws;

    lstm_layer_kernel<2,  true ><<<kB, 512, 0, stream>>>(x,  Wih0, Whh0, bih0, bhh0, hs);
    lstm_layer_kernel<64, true ><<<kB, 512, 0, stream>>>(hs, Wih1, Whh1, bih1, bhh1, hs);
    lstm_layer_kernel<64, false><<<kB, 512, 0, stream>>>(hs, Wih2, Whh2, bih2, bhh2, hs);
    out_proj_kernel<<<kB, 64, 0, stream>>>(hs, Wout, bout, (float*)d_out);
}